// Round 6
// baseline (479.987 us; speedup 1.0000x reference)
//
#include <hip/hip_runtime.h>
#include <hip/hip_bf16.h>
#include <hip/hip_cooperative_groups.h>

namespace cg = cooperative_groups;

#define D_ 1024
#define H_ 16
#define FF_ 2048
#define B_ 8
#define S_ 1027
#define MPAD_ 8320   /* 130 * 64 */
#define PSTR_ 1056   /* padded key stride for P (mult 32, covers 1027) */
#define EPS_ 1e-5f

typedef __hip_bfloat16 bf16;
typedef unsigned short u16;
typedef unsigned int u32;
typedef __attribute__((ext_vector_type(4))) float floatx4;
typedef __bf16 bf16x8 __attribute__((ext_vector_type(8)));

__device__ __forceinline__ float2 bfpair(u32 u) {
  union { u32 u; float f; } lo, hi;
  lo.u = u << 16; hi.u = u & 0xffff0000u;
  return make_float2(lo.f, hi.f);
}

__device__ __forceinline__ u32 f2bfbits(float f) {
  union { bf16 h; u16 u; } cv; cv.h = __float2bfloat16(f); return (u32)cv.u;
}

__device__ __forceinline__ float block_sum(float x, float* red) {
  const int t = threadIdx.x;
  __syncthreads();
  red[t] = x;
  __syncthreads();
  for (int s = 128; s > 0; s >>= 1) {
    if (t < s) red[t] += red[t + s];
    __syncthreads();
  }
  return red[0];
}

__device__ __forceinline__ float block_max(float x, float* red) {
  const int t = threadIdx.x;
  __syncthreads();
  red[t] = x;
  __syncthreads();
  for (int s = 128; s > 0; s >>= 1) {
    if (t < s) red[t] = fmaxf(red[t], red[t + s]);
    __syncthreads();
  }
  return red[0];
}

// --------------------------- shared-memory union ---------------------------
struct SMemD { float sc[PSTR_]; float red[256]; };
struct SMemJ { float v[D_]; float red[256]; };
union SMemU {
  float qs_[64];
  SMemD d;
  u16 tile[32 * 68];
  float lsf[8 * D_];
  u16 lsb[8 * FF_];
  SMemJ j;
};
struct SMem { SMemU u; float mn[8]; float rsd[8]; };

// ===========================================================================
// MEGA KERNEL (cooperative): all 10 stages, grid = 256 blocks x 256 threads.
// ===========================================================================
__global__ void __launch_bounds__(256) fused_kernel2(
    const float* __restrict__ x, const float* __restrict__ y,
    const float* __restrict__ cls, const float* __restrict__ sep,
    const float* __restrict__ px, const float* __restrict__ py,
    const float* __restrict__ Wqkv, const float* __restrict__ bqkv,
    const float* __restrict__ Wo, const float* __restrict__ bo,
    const float* __restrict__ W1, const float* __restrict__ b1,
    const float* __restrict__ W2, const float* __restrict__ b2,
    const float* __restrict__ g1, const float* __restrict__ be1,
    const float* __restrict__ g2, const float* __restrict__ be2,
    const int* __restrict__ xl, const int* __restrict__ yl,
    bf16* __restrict__ seq, float* __restrict__ q0s,
    u16* __restrict__ RT_hi, u16* __restrict__ RT_lo,
    float* __restrict__ S, u16* __restrict__ P, float* __restrict__ cbar,
    float* __restrict__ o0, float* __restrict__ att, bf16* __restrict__ f1,
    float* __restrict__ f2, float* __restrict__ outv) {
  cg::grid_group grid = cg::this_grid();
  const int bid = blockIdx.x, t = threadIdx.x;
  const int w = t >> 6, l = t & 63;
  const int lane16 = l & 15, quad = l >> 4;
  __shared__ SMem sm;

  // ---- Phase A1: q0s[r] = (Wq[r,:].cls + bq[r])/8, r = bid*4 + w ----------
  {
    const int r = bid * 4 + w;
    const float4* wr = (const float4*)(Wqkv + (size_t)r * D_) + l;
    const float4* cl4 = (const float4*)cls + l;
    float acc = 0.f;
#pragma unroll
    for (int c = 0; c < 4; ++c) {
      float4 wv = wr[c * 64], cv = cl4[c * 64];
      acc += wv.x * cv.x + wv.y * cv.y + wv.z * cv.z + wv.w * cv.w;
    }
#pragma unroll
    for (int off = 32; off > 0; off >>= 1) acc += __shfl_down(acc, off, 64);
    if (l == 0) q0s[r] = (acc + bqkv[r]) * 0.125f;
  }
  // ---- Phase A2: build merged seq (bf16), grid-stride over rows -----------
  for (int m = bid; m < B_ * S_; m += 256) {
    const int b = m / S_;
    const int s = m - b * S_;
    const float* src = nullptr;
    const float* add = nullptr;
    const int lx = xl[b], ly = yl[b];
    if (s == 0) src = cls;
    else if (s <= lx) { src = x + ((size_t)b * 512 + (s - 1)) * D_; add = px; }
    else if (s == lx + 1) src = sep;
    else if (s <= lx + ly + 1) { src = y + ((size_t)b * 512 + (s - lx - 2)) * D_; add = py; }
    else if (s == lx + ly + 2) src = sep;
    if (!src) continue;
    float4 sv = ((const float4*)src)[t];
    if (add) {
      float4 av = ((const float4*)add)[t];
      sv.x += av.x; sv.y += av.y; sv.z += av.z; sv.w += av.w;
    }
    uint2 o;
    o.x = f2bfbits(sv.x) | (f2bfbits(sv.y) << 16);
    o.y = f2bfbits(sv.z) | (f2bfbits(sv.w) << 16);
    ((uint2*)(seq + (size_t)m * D_))[t] = o;
  }
  grid.sync();

  // ---- Phase B: R-projection (hi/lo bf16), 64 blocks ----------------------
  if (bid < 64) {
    const int h = bid >> 2, cc = bid & 3;
    if (t < 64) sm.u.qs_[t] = q0s[h * 64 + t];
    __syncthreads();
    const int c = cc * 256 + t;
    const float* Wk = Wqkv + (size_t)(D_ + h * 64) * D_ + c;
    float acc = 0.f;
#pragma unroll 8
    for (int e = 0; e < 64; ++e) acc += Wk[(size_t)e * D_] * sm.u.qs_[e];
    const u32 hb = f2bfbits(acc);
    union { u32 u; float f; } hv; hv.u = hb << 16;
    RT_hi[h * D_ + c] = (u16)hb;
    RT_lo[h * D_ + c] = (u16)f2bfbits(acc - hv.f);
  }
  grid.sync();

  // ---- Phase C: scores via MFMA, 130 m-tiles ------------------------------
  if (bid < 130) {
    const int m0 = bid * 64;
    bool valid = false;
#pragma unroll
    for (int b = 0; b < B_; ++b) {
      int rs = b * S_, re = rs + xl[b] + yl[b] + 3;
      if (m0 < re && m0 + 64 > rs) valid = true;
    }
    if (valid) {
      const int row = m0 + w * 16 + lane16;
      const u16* arow = (const u16*)seq + (size_t)row * D_ + quad * 8;
      const u16* bh = RT_hi + lane16 * D_ + quad * 8;
      const u16* bl = RT_lo + lane16 * D_ + quad * 8;
      floatx4 acc = {};
#pragma unroll 4
      for (int kt = 0; kt < 32; ++kt) {
        bf16x8 a  = *(const bf16x8*)(arow + kt * 32);
        bf16x8 vh = *(const bf16x8*)(bh + kt * 32);
        bf16x8 vl = *(const bf16x8*)(bl + kt * 32);
        acc = __builtin_amdgcn_mfma_f32_16x16x32_bf16(a, vh, acc, 0, 0, 0);
        acc = __builtin_amdgcn_mfma_f32_16x16x32_bf16(a, vl, acc, 0, 0, 0);
      }
      *(floatx4*)&S[(size_t)lane16 * MPAD_ + m0 + w * 16 + quad * 4] = acc;
    }
  }
  grid.sync();

  // ---- Phase D: softmax per (h, b), 128 blocks ----------------------------
  if (bid < 128) {
    const int h = bid >> 3, b = bid & 7;
    const int n = xl[b] + yl[b] + 3;
    const float* Sp = S + (size_t)h * MPAD_ + b * S_;
    float lmax = -3.0e38f;
    for (int k = t; k < n; k += 256) {
      float s = Sp[k];
      sm.u.d.sc[k] = s;
      lmax = fmaxf(lmax, s);
    }
    const float gmax = block_max(lmax, sm.u.d.red);
    float lsum = 0.f;
    for (int k = t; k < n; k += 256) {
      float p = __expf(sm.u.d.sc[k] - gmax);
      sm.u.d.sc[k] = p;
      lsum += p;
    }
    const float inv = 1.0f / block_sum(lsum, sm.u.d.red);
    u16* Pp = P + (size_t)(h * 8 + b) * PSTR_;
    for (int k = t; k < PSTR_; k += 256)
      Pp[k] = (k < n) ? (u16)f2bfbits(sm.u.d.sc[k] * inv) : (u16)0;
  }
  grid.sync();

  // ---- Phase E: cbar via MFMA, 128 blocks (ct, b) -------------------------
  if (bid < 128) {
    const int ct = bid >> 3, b = bid & 7;
    const int c0 = ct * 64;
    const int n = xl[b] + yl[b] + 3;
    const int nkt = (n + 31) >> 5;
    const int sk = t >> 3, scg = (t & 7) * 8;
    const u16* Pp = P + (size_t)(lane16 * 8 + b) * PSTR_;
    floatx4 acc = {};
    for (int kt = 0; kt < nkt; ++kt) {
      const int k0 = kt * 32;
      __syncthreads();
      uint4 v = make_uint4(0u, 0u, 0u, 0u);
      if (k0 + sk < n)
        v = *(const uint4*)((const u16*)seq + (size_t)(b * S_ + k0 + sk) * D_ + c0 + scg);
      *(uint2*)&sm.u.tile[sk * 68 + scg]     = make_uint2(v.x, v.y);
      *(uint2*)&sm.u.tile[sk * 68 + scg + 4] = make_uint2(v.z, v.w);
      __syncthreads();
      bf16x8 a = *(const bf16x8*)(Pp + k0 + quad * 8);
      union { bf16x8 v; u16 u[8]; } bu;
#pragma unroll
      for (int j = 0; j < 8; ++j)
        bu.u[j] = sm.u.tile[(quad * 8 + j) * 68 + w * 16 + lane16];
      acc = __builtin_amdgcn_mfma_f32_16x16x32_bf16(a, bu.v, acc, 0, 0, 0);
    }
#pragma unroll
    for (int r = 0; r < 4; ++r)
      cbar[(size_t)(b * 16 + quad * 4 + r) * D_ + c0 + w * 16 + lane16] = acc[r];
  }
  grid.sync();

  // ---- Phase F: o0 = Wv . cbar + bv, 256 blocks x 4 rows ------------------
  {
    const int hoff = (bid >> 4) * D_;
#pragma unroll
    for (int i = 0; i < 8; ++i) {
      int flat = (t + i * 256) * 4;
      int b = flat >> 10, k = flat & 1023;
      *(float4*)&sm.u.lsf[flat] = *(const float4*)(cbar + (size_t)b * 16384 + hoff + k);
    }
    __syncthreads();
    const int r = bid * 4 + w;
    const float* Wv = Wqkv + (size_t)2048 * D_;
    float acc[8] = {};
#pragma unroll
    for (int ch = 0; ch < 4; ++ch) {
      float4 wv = *(const float4*)(Wv + (size_t)r * D_ + ch * 256 + l * 4);
#pragma unroll
      for (int b = 0; b < 8; ++b) {
        const float* p = &sm.u.lsf[b * D_ + ch * 256 + l * 4];
        acc[b] += wv.x * p[0] + wv.y * p[1] + wv.z * p[2] + wv.w * p[3];
      }
    }
#pragma unroll
    for (int off = 32; off > 0; off >>= 1)
#pragma unroll
      for (int b = 0; b < 8; ++b) acc[b] += __shfl_down(acc[b], off, 64);
    if (l == 0) {
      const float bs = bqkv[2048 + r];
#pragma unroll
      for (int b = 0; b < 8; ++b) o0[(size_t)b * D_ + r] = acc[b] + bs;
    }
  }
  grid.sync();

  // ---- Phase G: att = Wo . o0 + bo, 256 blocks x 4 rows -------------------
  {
#pragma unroll
    for (int i = 0; i < 8; ++i) {
      int flat = (t + i * 256) * 4;
      *(float4*)&sm.u.lsf[flat] = *(const float4*)(o0 + flat);
    }
    __syncthreads();
    const int r = bid * 4 + w;
    float acc[8] = {};
#pragma unroll
    for (int ch = 0; ch < 4; ++ch) {
      float4 wv = *(const float4*)(Wo + (size_t)r * D_ + ch * 256 + l * 4);
#pragma unroll
      for (int b = 0; b < 8; ++b) {
        const float* p = &sm.u.lsf[b * D_ + ch * 256 + l * 4];
        acc[b] += wv.x * p[0] + wv.y * p[1] + wv.z * p[2] + wv.w * p[3];
      }
    }
#pragma unroll
    for (int off = 32; off > 0; off >>= 1)
#pragma unroll
      for (int b = 0; b < 8; ++b) acc[b] += __shfl_down(acc[b], off, 64);
    if (l == 0) {
      const float bs = bo[r];
#pragma unroll
      for (int b = 0; b < 8; ++b) att[(size_t)b * D_ + r] = acc[b] + bs;
    }
  }
  grid.sync();

  // ---- Phase H: LN1 + W1 + ReLU -> f1 (bf16), 256 blocks x 8 rows ---------
  {
    float4 cv = ((const float4*)cls)[t];
#pragma unroll
    for (int i = 0; i < 8; ++i) {
      float4 a = ((const float4*)(att + (size_t)i * D_))[t];
      a.x += cv.x; a.y += cv.y; a.z += cv.z; a.w += cv.w;
      *(float4*)&sm.u.lsf[i * D_ + t * 4] = a;
    }
    __syncthreads();
    {
      const int b = t >> 5, j = t & 31;
      const float* base = &sm.u.lsf[b * D_ + j * 32];
      float s = 0.f, s2 = 0.f;
#pragma unroll
      for (int k = 0; k < 32; ++k) { float v = base[k]; s += v; s2 += v * v; }
#pragma unroll
      for (int off = 16; off > 0; off >>= 1) {
        s += __shfl_down(s, off, 32);
        s2 += __shfl_down(s2, off, 32);
      }
      if (j == 0) {
        float mean = s * (1.f / D_);
        sm.mn[b] = mean;
        sm.rsd[b] = rsqrtf(s2 * (1.f / D_) - mean * mean + EPS_);
      }
    }
    __syncthreads();
    {
      const int b = t >> 5, j = t & 31;
      const float mean = sm.mn[b], rs = sm.rsd[b];
      float* base = &sm.u.lsf[b * D_ + j * 32];
      const float* gp = &g1[j * 32];
      const float* bp = &be1[j * 32];
#pragma unroll
      for (int k = 0; k < 32; ++k)
        base[k] = (base[k] - mean) * rs * gp[k] + bp[k];
    }
    __syncthreads();
#pragma unroll
    for (int rr = 0; rr < 2; ++rr) {
      const int r = bid * 8 + rr * 4 + w;
      float acc[8] = {};
#pragma unroll
      for (int ch = 0; ch < 4; ++ch) {
        float4 wv = *(const float4*)(W1 + (size_t)r * D_ + ch * 256 + l * 4);
#pragma unroll
        for (int b = 0; b < 8; ++b) {
          const float* p = &sm.u.lsf[b * D_ + ch * 256 + l * 4];
          acc[b] += wv.x * p[0] + wv.y * p[1] + wv.z * p[2] + wv.w * p[3];
        }
      }
#pragma unroll
      for (int off = 32; off > 0; off >>= 1)
#pragma unroll
        for (int b = 0; b < 8; ++b) acc[b] += __shfl_down(acc[b], off, 64);
      if (l == 0) {
        const float bs = b1[r];
#pragma unroll
        for (int b = 0; b < 8; ++b)
          f1[(size_t)b * FF_ + r] = __float2bfloat16(fmaxf(acc[b] + bs, 0.f));
      }
    }
  }
  grid.sync();

  // ---- Phase I: f2 = W2 . f1 + b2, 256 blocks x 4 rows --------------------
  {
#pragma unroll
    for (int i = 0; i < 8; ++i) {
      int flat = (t + i * 256) * 8;
      *(uint4*)&sm.u.lsb[flat] = *(const uint4*)((const u16*)f1 + flat);
    }
    __syncthreads();
    const int r = bid * 4 + w;
    float acc[8] = {};
#pragma unroll
    for (int ch = 0; ch < 8; ++ch) {
      float4 wv = *(const float4*)(W2 + (size_t)r * FF_ + ch * 256 + l * 4);
#pragma unroll
      for (int b = 0; b < 8; ++b) {
        uint2 u = *(const uint2*)&sm.u.lsb[b * FF_ + ch * 256 + l * 4];
        float2 p0 = bfpair(u.x), p1 = bfpair(u.y);
        acc[b] += wv.x * p0.x + wv.y * p0.y + wv.z * p1.x + wv.w * p1.y;
      }
    }
#pragma unroll
    for (int off = 32; off > 0; off >>= 1)
#pragma unroll
      for (int b = 0; b < 8; ++b) acc[b] += __shfl_down(acc[b], off, 64);
    if (l == 0) {
      const float bs = b2[r];
#pragma unroll
      for (int b = 0; b < 8; ++b) f2[(size_t)b * D_ + r] = acc[b] + bs;
    }
  }
  grid.sync();

  // ---- Phase J: out = LN2( LN1(cls+att) + f2 ), 8 blocks ------------------
  if (bid < 8) {
    const int b = bid;
    for (int i = t; i < D_; i += 256) sm.u.j.v[i] = cls[i] + att[(size_t)b * D_ + i];
    __syncthreads();
    float ls = 0.f;
    for (int i = t; i < D_; i += 256) ls += sm.u.j.v[i];
    const float m1 = block_sum(ls, sm.u.j.red) * (1.f / D_);
    float lv = 0.f;
    for (int i = t; i < D_; i += 256) { float dk = sm.u.j.v[i] - m1; lv += dk * dk; }
    const float rs1 = rsqrtf(block_sum(lv, sm.u.j.red) * (1.f / D_) + EPS_);
    __syncthreads();
    for (int i = t; i < D_; i += 256)
      sm.u.j.v[i] = (sm.u.j.v[i] - m1) * rs1 * g1[i] + be1[i] + f2[(size_t)b * D_ + i];
    __syncthreads();
    float ls2 = 0.f;
    for (int i = t; i < D_; i += 256) ls2 += sm.u.j.v[i];
    const float m2 = block_sum(ls2, sm.u.j.red) * (1.f / D_);
    float lv2 = 0.f;
    for (int i = t; i < D_; i += 256) { float dk = sm.u.j.v[i] - m2; lv2 += dk * dk; }
    const float rs2 = rsqrtf(block_sum(lv2, sm.u.j.red) * (1.f / D_) + EPS_);
    for (int i = t; i < D_; i += 256)
      outv[(size_t)b * D_ + i] = (sm.u.j.v[i] - m2) * rs2 * g2[i] + be2[i];
  }
}

// ===========================================================================
// FALLBACK PATH: the proven R5 10-kernel pipeline (used if coop launch fails)
// ===========================================================================
__global__ void __launch_bounds__(256) build_seq_kernel(
    const float* __restrict__ x, const float* __restrict__ y,
    const float* __restrict__ cls, const float* __restrict__ sep,
    const float* __restrict__ px, const float* __restrict__ py,
    const int* __restrict__ x_len, const int* __restrict__ y_len,
    bf16* __restrict__ seq) {
  const int m = blockIdx.x, t = threadIdx.x;
  const int b = m / S_;
  const int s = m - b * S_;
  if (b >= B_) return;
  const float* src = nullptr;
  const float* add = nullptr;
  const int lx = x_len[b], ly = y_len[b];
  if (s == 0) src = cls;
  else if (s <= lx) { src = x + ((size_t)b * 512 + (s - 1)) * D_; add = px; }
  else if (s == lx + 1) src = sep;
  else if (s <= lx + ly + 1) { src = y + ((size_t)b * 512 + (s - lx - 2)) * D_; add = py; }
  else if (s == lx + ly + 2) src = sep;
  if (!src) return;
  float4 sv = ((const float4*)src)[t];
  if (add) {
    float4 av = ((const float4*)add)[t];
    sv.x += av.x; sv.y += av.y; sv.z += av.z; sv.w += av.w;
  }
  uint2 o;
  o.x = f2bfbits(sv.x) | (f2bfbits(sv.y) << 16);
  o.y = f2bfbits(sv.z) | (f2bfbits(sv.w) << 16);
  ((uint2*)(seq + (size_t)m * D_))[t] = o;
}

__global__ void __launch_bounds__(256) qr_kernel(
    const float* __restrict__ cls, const float* __restrict__ Wqkv,
    const float* __restrict__ bqkv, u16* __restrict__ RT_hi,
    u16* __restrict__ RT_lo) {
  const int cc = blockIdx.x, h = blockIdx.y, t = threadIdx.x;
  __shared__ float clds[D_];
  __shared__ float qs[64];
  *(float4*)&clds[t * 4] = ((const float4*)cls)[t];
  __syncthreads();
  const int w = t >> 6, l = t & 63;
#pragma unroll 2
  for (int e8 = 0; e8 < 16; ++e8) {
    const int e = e8 * 4 + w;
    const float4* wr = (const float4*)(Wqkv + (size_t)(h * 64 + e) * D_) + l;
    float acc = 0.f;
#pragma unroll
    for (int c = 0; c < 4; ++c) {
      float4 wv = wr[c * 64];
      const float* cp = &clds[c * 256 + l * 4];
      acc += wv.x * cp[0] + wv.y * cp[1] + wv.z * cp[2] + wv.w * cp[3];
    }
#pragma unroll
    for (int off = 32; off > 0; off >>= 1) acc += __shfl_down(acc, off, 64);
    if (l == 0) qs[e] = (acc + bqkv[h * 64 + e]) * 0.125f;
  }
  __syncthreads();
  const int c = cc * 256 + t;
  const float* Wk = Wqkv + (size_t)(D_ + h * 64) * D_ + c;
  float acc = 0.f;
#pragma unroll 8
  for (int e = 0; e < 64; ++e) acc += Wk[(size_t)e * D_] * qs[e];
  const u32 hb = f2bfbits(acc);
  union { u32 u; float f; } hv; hv.u = hb << 16;
  RT_hi[h * D_ + c] = (u16)hb;
  RT_lo[h * D_ + c] = (u16)f2bfbits(acc - hv.f);
}

__global__ void __launch_bounds__(256) scores_kernel(
    const bf16* __restrict__ seq, const u16* __restrict__ RT_hi,
    const u16* __restrict__ RT_lo, const int* __restrict__ x_len,
    const int* __restrict__ y_len, float* __restrict__ S) {
  const int m0 = blockIdx.x * 64;
  bool valid = false;
#pragma unroll
  for (int b = 0; b < B_; ++b) {
    int rs = b * S_, re = rs + x_len[b] + y_len[b] + 3;
    if (m0 < re && m0 + 64 > rs) valid = true;
  }
  if (!valid) return;
  const int t = threadIdx.x;
  const int w = t >> 6, lane = t & 63, lane16 = lane & 15, quad = lane >> 4;
  const int row = m0 + w * 16 + lane16;
  const u16* arow = (const u16*)seq + (size_t)row * D_ + quad * 8;
  const u16* bh = RT_hi + lane16 * D_ + quad * 8;
  const u16* bl = RT_lo + lane16 * D_ + quad * 8;
  floatx4 acc = {};
#pragma unroll 4
  for (int kt = 0; kt < 32; ++kt) {
    bf16x8 a  = *(const bf16x8*)(arow + kt * 32);
    bf16x8 vh = *(const bf16x8*)(bh + kt * 32);
    bf16x8 vl = *(const bf16x8*)(bl + kt * 32);
    acc = __builtin_amdgcn_mfma_f32_16x16x32_bf16(a, vh, acc, 0, 0, 0);
    acc = __builtin_amdgcn_mfma_f32_16x16x32_bf16(a, vl, acc, 0, 0, 0);
  }
  *(floatx4*)&S[(size_t)lane16 * MPAD_ + m0 + w * 16 + quad * 4] = acc;
}

__global__ void __launch_bounds__(256) softmax_kernel(
    const float* __restrict__ S, const int* __restrict__ x_len,
    const int* __restrict__ y_len, u16* __restrict__ P) {
  const int h = blockIdx.x, b = blockIdx.y, t = threadIdx.x;
  const int n = x_len[b] + y_len[b] + 3;
  __shared__ float sc[PSTR_];
  __shared__ float red[256];
  const float* Sp = S + (size_t)h * MPAD_ + b * S_;
  float lmax = -3.0e38f;
  for (int k = t; k < n; k += 256) {
    float s = Sp[k];
    sc[k] = s;
    lmax = fmaxf(lmax, s);
  }
  const float gmax = block_max(lmax, red);
  float lsum = 0.f;
  for (int k = t; k < n; k += 256) {
    float p = __expf(sc[k] - gmax);
    sc[k] = p;
    lsum += p;
  }
  const float inv = 1.0f / block_sum(lsum, red);
  u16* Pp = P + (size_t)(h * 8 + b) * PSTR_;
  for (int k = t; k < PSTR_; k += 256)
    Pp[k] = (k < n) ? (u16)f2bfbits(sc[k] * inv) : (u16)0;
}

__global__ void __launch_bounds__(256) cbar_kernel(
    const bf16* __restrict__ seq, const u16* __restrict__ P,
    const int* __restrict__ x_len, const int* __restrict__ y_len,
    float* __restrict__ cbar) {
  const int ct = blockIdx.x, b = blockIdx.y, t = threadIdx.x;
  const int c0 = ct * 64;
  const int n = x_len[b] + y_len[b] + 3;
  const int nkt = (n + 31) >> 5;
  __shared__ u16 tile[32 * 68];
  const int w = t >> 6, lane = t & 63, lane16 = lane & 15, quad = lane >> 4;
  const int sk = t >> 3, scg = (t & 7) * 8;
  floatx4 acc = {};
  for (int kt = 0; kt < nkt; ++kt) {
    const int k0 = kt * 32;
    __syncthreads();
    uint4 v = make_uint4(0u, 0u, 0u, 0u);
    if (k0 + sk < n)
      v = *(const uint4*)((const u16*)seq + (size_t)(b * S_ + k0 + sk) * D_ + c0 + scg);
    *(uint2*)&tile[sk * 68 + scg]     = make_uint2(v.x, v.y);
    *(uint2*)&tile[sk * 68 + scg + 4] = make_uint2(v.z, v.w);
    __syncthreads();
    bf16x8 a = *(const bf16x8*)(P + (size_t)(lane16 * 8 + b) * PSTR_ + k0 + quad * 8);
    union { bf16x8 v; u16 u[8]; } bu;
#pragma unroll
    for (int j = 0; j < 8; ++j)
      bu.u[j] = tile[(quad * 8 + j) * 68 + w * 16 + lane16];
    acc = __builtin_amdgcn_mfma_f32_16x16x32_bf16(a, bu.v, acc, 0, 0, 0);
  }
#pragma unroll
  for (int r = 0; r < 4; ++r)
    cbar[(size_t)(b * 16 + quad * 4 + r) * D_ + c0 + w * 16 + lane16] = acc[r];
}

template <int K, int N, int BSTR, bool INBF, bool OUTBF, bool RELU, bool PERHEAD>
__global__ void __launch_bounds__(256) gemv8_kernel(
    const void* __restrict__ in_, const float* __restrict__ W,
    const float* __restrict__ bias, void* __restrict__ out_) {
  const int t = threadIdx.x;
  const int hoff = PERHEAD ? ((blockIdx.x * 4) >> 6) * D_ : 0;
  __shared__ u16 lsb[INBF ? 8 * K : 1];
  __shared__ float lsf[INBF ? 1 : 8 * K];
  if (INBF) {
    const u16* in = (const u16*)in_;
    const int per = 8 * K / (256 * 8);
#pragma unroll
    for (int i = 0; i < per; ++i) {
      int flat = (t + i * 256) * 8;
      int b = flat / K, k = flat % K;
      *(uint4*)&lsb[flat] = *(const uint4*)(in + (size_t)b * BSTR + hoff + k);
    }
  } else {
    const float* in = (const float*)in_;
    const int per = 8 * K / (256 * 4);
#pragma unroll
    for (int i = 0; i < per; ++i) {
      int flat = (t + i * 256) * 4;
      int b = flat / K, k = flat % K;
      *(float4*)&lsf[flat] = *(const float4*)(in + (size_t)b * BSTR + hoff + k);
    }
  }
  __syncthreads();
  const int w = t >> 6, l = t & 63;
  const int r = blockIdx.x * 4 + w;
  float acc[8] = {};
#pragma unroll
  for (int ch = 0; ch < K / 256; ++ch) {
    float4 wv = *(const float4*)(W + (size_t)r * K + ch * 256 + l * 4);
#pragma unroll
    for (int b = 0; b < 8; ++b) {
      float i0, i1, i2, i3;
      if (INBF) {
        uint2 u = *(const uint2*)&lsb[b * K + ch * 256 + l * 4];
        float2 p0 = bfpair(u.x), p1 = bfpair(u.y);
        i0 = p0.x; i1 = p0.y; i2 = p1.x; i3 = p1.y;
      } else {
        const float* p = &lsf[b * K + ch * 256 + l * 4];
        i0 = p[0]; i1 = p[1]; i2 = p[2]; i3 = p[3];
      }
      acc[b] += wv.x * i0 + wv.y * i1 + wv.z * i2 + wv.w * i3;
    }
  }
#pragma unroll
  for (int off = 32; off > 0; off >>= 1)
#pragma unroll
    for (int b = 0; b < 8; ++b) acc[b] += __shfl_down(acc[b], off, 64);
  if (l == 0) {
    const float bs = bias[r];
#pragma unroll
    for (int b = 0; b < 8; ++b) {
      float v = acc[b] + bs;
      if (RELU) v = fmaxf(v, 0.f);
      if (OUTBF) ((bf16*)out_)[(size_t)b * N + r] = __float2bfloat16(v);
      else       ((float*)out_)[(size_t)b * N + r] = v;
    }
  }
}

__global__ void __launch_bounds__(256) w1ln_kernel(
    const float* __restrict__ att, const float* __restrict__ cls,
    const float* __restrict__ g1, const float* __restrict__ be1,
    const float* __restrict__ W1, const float* __restrict__ b1,
    bf16* __restrict__ f1) {
  const int t = threadIdx.x;
  __shared__ float ls[8 * D_];
  __shared__ float mn[8], rsd[8];
  float4 cv = ((const float4*)cls)[t];
#pragma unroll
  for (int i = 0; i < 8; ++i) {
    float4 a = ((const float4*)(att + (size_t)i * D_))[t];
    a.x += cv.x; a.y += cv.y; a.z += cv.z; a.w += cv.w;
    *(float4*)&ls[i * D_ + t * 4] = a;
  }
  __syncthreads();
  {
    const int b = t >> 5, j = t & 31;
    const float* base = &ls[b * D_ + j * 32];
    float s = 0.f, s2 = 0.f;
#pragma unroll
    for (int k = 0; k < 32; ++k) { float v = base[k]; s += v; s2 += v * v; }
#pragma unroll
    for (int off = 16; off > 0; off >>= 1) {
      s += __shfl_down(s, off, 32);
      s2 += __shfl_down(s2, off, 32);
    }
    if (j == 0) {
      float mean = s * (1.f / D_);
      mn[b] = mean;
      rsd[b] = rsqrtf(s2 * (1.f / D_) - mean * mean + EPS_);
    }
  }
  __syncthreads();
  {
    const int b = t >> 5, j = t & 31;
    const float mean = mn[b], rs = rsd[b];
    float* base = &ls[b * D_ + j * 32];
    const float* gp = &g1[j * 32];
    const float* bp = &be1[j * 32];
#pragma unroll
    for (int k = 0; k < 32; ++k)
      base[k] = (base[k] - mean) * rs * gp[k] + bp[k];
  }
  __syncthreads();
  const int w = t >> 6, l = t & 63;
  const int r = blockIdx.x * 4 + w;
  float acc[8] = {};
#pragma unroll
  for (int ch = 0; ch < 4; ++ch) {
    float4 wv = *(const float4*)(W1 + (size_t)r * D_ + ch * 256 + l * 4);
#pragma unroll
    for (int b = 0; b < 8; ++b) {
      const float* p = &ls[b * D_ + ch * 256 + l * 4];
      acc[b] += wv.x * p[0] + wv.y * p[1] + wv.z * p[2] + wv.w * p[3];
    }
  }
#pragma unroll
  for (int off = 32; off > 0; off >>= 1)
#pragma unroll
    for (int b = 0; b < 8; ++b) acc[b] += __shfl_down(acc[b], off, 64);
  if (l == 0) {
    const float bs = b1[r];
#pragma unroll
    for (int b = 0; b < 8; ++b)
      f1[(size_t)b * FF_ + r] = __float2bfloat16(fmaxf(acc[b] + bs, 0.f));
  }
}

__global__ void __launch_bounds__(256) ln2_kernel(
    const float* __restrict__ cls, const float* __restrict__ att,
    const float* __restrict__ f2, const float* __restrict__ g1,
    const float* __restrict__ be1, const float* __restrict__ g2,
    const float* __restrict__ be2, float* __restrict__ out) {
  const int b = blockIdx.x, t = threadIdx.x;
  __shared__ float v[D_];
  __shared__ float red[256];
  for (int i = t; i < D_; i += 256) v[i] = cls[i] + att[(size_t)b * D_ + i];
  __syncthreads();
  float ls = 0.f;
  for (int i = t; i < D_; i += 256) ls += v[i];
  const float m1 = block_sum(ls, red) * (1.f / D_);
  float lv = 0.f;
  for (int i = t; i < D_; i += 256) { float dk = v[i] - m1; lv += dk * dk; }
  const float rs1 = rsqrtf(block_sum(lv, red) * (1.f / D_) + EPS_);
  __syncthreads();
  for (int i = t; i < D_; i += 256)
    v[i] = (v[i] - m1) * rs1 * g1[i] + be1[i] + f2[(size_t)b * D_ + i];
  __syncthreads();
  float ls2 = 0.f;
  for (int i = t; i < D_; i += 256) ls2 += v[i];
  const float m2 = block_sum(ls2, red) * (1.f / D_);
  float lv2 = 0.f;
  for (int i = t; i < D_; i += 256) { float dk = v[i] - m2; lv2 += dk * dk; }
  const float rs2 = rsqrtf(block_sum(lv2, red) * (1.f / D_) + EPS_);
  for (int i = t; i < D_; i += 256)
    out[(size_t)b * D_ + i] = (v[i] - m2) * rs2 * g2[i] + be2[i];
}

// ---------------------------------------------------------------------------
extern "C" void kernel_launch(void* const* d_in, const int* in_sizes, int n_in,
                              void* d_out, int out_size, void* d_ws, size_t ws_size,
                              hipStream_t stream) {
  (void)in_sizes; (void)n_in; (void)out_size; (void)ws_size;
  const float* x    = (const float*)d_in[0];
  const float* y    = (const float*)d_in[1];
  const float* cls  = (const float*)d_in[2];
  const float* sep  = (const float*)d_in[3];
  const float* px   = (const float*)d_in[4];
  const float* py   = (const float*)d_in[5];
  const float* Wqkv = (const float*)d_in[6];
  const float* bqkv = (const float*)d_in[7];
  const float* Wo   = (const float*)d_in[8];
  const float* bo   = (const float*)d_in[9];
  const float* W1   = (const float*)d_in[10];
  const float* b1   = (const float*)d_in[11];
  const float* W2   = (const float*)d_in[12];
  const float* b2   = (const float*)d_in[13];
  const float* g1   = (const float*)d_in[14];
  const float* be1  = (const float*)d_in[15];
  const float* g2   = (const float*)d_in[16];
  const float* be2  = (const float*)d_in[17];
  const int* xl     = (const int*)d_in[18];
  const int* yl     = (const int*)d_in[19];

  char* ws = (char*)d_ws;
  bf16*  seq   = (bf16*)(ws);                 // 17,039,360
  float* q0s   = (float*)(ws + 17039360);     //   4,096
  u16*   RT_hi = (u16*)(ws + 17043456);       //  32,768
  u16*   RT_lo = (u16*)(ws + 17076224);       //  32,768
  float* S     = (float*)(ws + 17108992);     // 532,480
  u16*   P     = (u16*)(ws + 17641472);       // 270,336
  float* cbar  = (float*)(ws + 17911808);     // 524,288
  float* o0    = (float*)(ws + 18436096);     //  32,768
  float* att   = (float*)(ws + 18468864);     //  32,768
  bf16*  f1    = (bf16*)(ws + 18501632);      //  32,768
  float* f2    = (float*)(ws + 18534400);     //  32,768
  float* outv  = (float*)d_out;

  void* args[] = {
    (void*)&x, (void*)&y, (void*)&cls, (void*)&sep, (void*)&px, (void*)&py,
    (void*)&Wqkv, (void*)&bqkv, (void*)&Wo, (void*)&bo, (void*)&W1, (void*)&b1,
    (void*)&W2, (void*)&b2, (void*)&g1, (void*)&be1, (void*)&g2, (void*)&be2,
    (void*)&xl, (void*)&yl, (void*)&seq, (void*)&q0s, (void*)&RT_hi,
    (void*)&RT_lo, (void*)&S, (void*)&P, (void*)&cbar, (void*)&o0, (void*)&att,
    (void*)&f1, (void*)&f2, (void*)&outv
  };
  hipError_t err = hipLaunchCooperativeKernel(
      (const void*)fused_kernel2, dim3(256), dim3(256), args, 0, stream);
  if (err != hipSuccess) {
    build_seq_kernel<<<MPAD_, 256, 0, stream>>>(x, y, cls, sep, px, py, xl, yl, seq);
    qr_kernel<<<dim3(4, 16), 256, 0, stream>>>(cls, Wqkv, bqkv, RT_hi, RT_lo);
    scores_kernel<<<130, 256, 0, stream>>>(seq, RT_hi, RT_lo, xl, yl, S);
    softmax_kernel<<<dim3(16, 8), 256, 0, stream>>>(S, xl, yl, P);
    cbar_kernel<<<dim3(16, 8), 256, 0, stream>>>(seq, P, xl, yl, cbar);
    gemv8_kernel<1024, 1024, 16384, false, false, false, true>
        <<<256, 256, 0, stream>>>(cbar, Wqkv + (size_t)2048 * 1024, bqkv + 2048, o0);
    gemv8_kernel<1024, 1024, 1024, false, false, false, false>
        <<<256, 256, 0, stream>>>(o0, Wo, bo, att);
    w1ln_kernel<<<512, 256, 0, stream>>>(att, cls, g1, be1, W1, b1, f1);
    gemv8_kernel<2048, 1024, 2048, true, false, false, false>
        <<<256, 256, 0, stream>>>(f1, W2, b2, f2);
    ln2_kernel<<<B_, 256, 0, stream>>>(cls, att, f2, g1, be1, g2, be2, outv);
  }
}

// Round 7
// 211.762 us; speedup vs baseline: 2.2666x; 2.2666x over previous
//
#include <hip/hip_runtime.h>
#include <hip/hip_bf16.h>

#define D_ 1024
#define H_ 16
#define FF_ 2048
#define B_ 8
#define S_ 1027
#define MPAD_ 8320   /* 130 * 64 */
#define PLSTR_ 1060  /* LDS p stride in u16: 530 words, 530%32=18 -> conflict-free */
#define EPS_ 1e-5f

typedef __hip_bfloat16 bf16;
typedef unsigned short u16;
typedef unsigned int u32;
typedef __attribute__((ext_vector_type(4))) float floatx4;
typedef __bf16 bf16x8 __attribute__((ext_vector_type(8)));

__device__ __forceinline__ float2 bfpair(u32 u) {
  union { u32 u; float f; } lo, hi;
  lo.u = u << 16; hi.u = u & 0xffff0000u;
  return make_float2(lo.f, hi.f);
}

__device__ __forceinline__ u32 f2bfbits(float f) {
  union { bf16 h; u16 u; } cv; cv.h = __float2bfloat16(f); return (u32)cv.u;
}

__device__ __forceinline__ float block_sum(float x, float* red) {
  const int t = threadIdx.x;
  __syncthreads();
  red[t] = x;
  __syncthreads();
  for (int s = 128; s > 0; s >>= 1) {
    if (t < s) red[t] += red[t + s];
    __syncthreads();
  }
  return red[0];
}

// ---------------------------------------------------------------------------
// K1: merged build_seq (blocks 0..MPAD_-1) + qr (blocks MPAD_..MPAD_+63).
// build_seq: merged sequence as bf16, coalesced, invalid rows not written.
// qr: q0[64] for head h computed in-block, then R[c] split to bf16 hi/lo.
// ---------------------------------------------------------------------------
__global__ void __launch_bounds__(256) seq_qr_kernel(
    const float* __restrict__ x, const float* __restrict__ y,
    const float* __restrict__ cls, const float* __restrict__ sep,
    const float* __restrict__ px, const float* __restrict__ py,
    const float* __restrict__ Wqkv, const float* __restrict__ bqkv,
    const int* __restrict__ x_len, const int* __restrict__ y_len,
    bf16* __restrict__ seq, u16* __restrict__ RT_hi, u16* __restrict__ RT_lo) {
  const int t = threadIdx.x;
  if (blockIdx.x < MPAD_) {
    const int m = blockIdx.x;
    const int b = m / S_;
    const int s = m - b * S_;
    if (b >= B_) return;
    const float* src = nullptr;
    const float* add = nullptr;
    const int lx = x_len[b], ly = y_len[b];
    if (s == 0) src = cls;
    else if (s <= lx) { src = x + ((size_t)b * 512 + (s - 1)) * D_; add = px; }
    else if (s == lx + 1) src = sep;
    else if (s <= lx + ly + 1) { src = y + ((size_t)b * 512 + (s - lx - 2)) * D_; add = py; }
    else if (s == lx + ly + 2) src = sep;
    if (!src) return;
    float4 sv = ((const float4*)src)[t];
    if (add) {
      float4 av = ((const float4*)add)[t];
      sv.x += av.x; sv.y += av.y; sv.z += av.z; sv.w += av.w;
    }
    uint2 o;
    o.x = f2bfbits(sv.x) | (f2bfbits(sv.y) << 16);
    o.y = f2bfbits(sv.z) | (f2bfbits(sv.w) << 16);
    ((uint2*)(seq + (size_t)m * D_))[t] = o;
    return;
  }
  // ---- qr body ----
  const int bid2 = blockIdx.x - MPAD_;
  const int cc = bid2 & 3, h = bid2 >> 2;
  __shared__ float clds[D_];
  __shared__ float qs[64];
  *(float4*)&clds[t * 4] = ((const float4*)cls)[t];
  __syncthreads();
  const int w = t >> 6, l = t & 63;
#pragma unroll 2
  for (int e8 = 0; e8 < 16; ++e8) {
    const int e = e8 * 4 + w;
    const float4* wr = (const float4*)(Wqkv + (size_t)(h * 64 + e) * D_) + l;
    float acc = 0.f;
#pragma unroll
    for (int c = 0; c < 4; ++c) {
      float4 wv = wr[c * 64];
      const float* cp = &clds[c * 256 + l * 4];
      acc += wv.x * cp[0] + wv.y * cp[1] + wv.z * cp[2] + wv.w * cp[3];
    }
#pragma unroll
    for (int off = 32; off > 0; off >>= 1) acc += __shfl_down(acc, off, 64);
    if (l == 0) qs[e] = (acc + bqkv[h * 64 + e]) * 0.125f;
  }
  __syncthreads();
  const int c = cc * 256 + t;
  const float* Wk = Wqkv + (size_t)(D_ + h * 64) * D_ + c;
  float acc = 0.f;
#pragma unroll 8
  for (int e = 0; e < 64; ++e) acc += Wk[(size_t)e * D_] * qs[e];
  const u32 hb = f2bfbits(acc);
  union { u32 u; float f; } hv; hv.u = hb << 16;
  RT_hi[h * D_ + c] = (u16)hb;
  RT_lo[h * D_ + c] = (u16)f2bfbits(acc - hv.f);
}

// ---------------------------------------------------------------------------
// K2: scores S[h][m] = seq[m,:] . R[:,h] via MFMA 16x16x32 (hi+lo).
// Grid 130 m-tiles of 64 rows; early-exit fully-invalid tiles.
// ---------------------------------------------------------------------------
__global__ void __launch_bounds__(256) scores_kernel(
    const bf16* __restrict__ seq, const u16* __restrict__ RT_hi,
    const u16* __restrict__ RT_lo, const int* __restrict__ x_len,
    const int* __restrict__ y_len, float* __restrict__ S) {
  const int m0 = blockIdx.x * 64;
  bool valid = false;
#pragma unroll
  for (int b = 0; b < B_; ++b) {
    int rs = b * S_, re = rs + x_len[b] + y_len[b] + 3;
    if (m0 < re && m0 + 64 > rs) valid = true;
  }
  if (!valid) return;
  const int t = threadIdx.x;
  const int w = t >> 6, lane = t & 63, lane16 = lane & 15, quad = lane >> 4;
  const int row = m0 + w * 16 + lane16;
  const u16* arow = (const u16*)seq + (size_t)row * D_ + quad * 8;
  const u16* bh = RT_hi + lane16 * D_ + quad * 8;
  const u16* bl = RT_lo + lane16 * D_ + quad * 8;
  floatx4 acc = {};
#pragma unroll 4
  for (int kt = 0; kt < 32; ++kt) {
    bf16x8 a  = *(const bf16x8*)(arow + kt * 32);
    bf16x8 vh = *(const bf16x8*)(bh + kt * 32);
    bf16x8 vl = *(const bf16x8*)(bl + kt * 32);
    acc = __builtin_amdgcn_mfma_f32_16x16x32_bf16(a, vh, acc, 0, 0, 0);
    acc = __builtin_amdgcn_mfma_f32_16x16x32_bf16(a, vl, acc, 0, 0, 0);
  }
  *(floatx4*)&S[(size_t)lane16 * MPAD_ + m0 + w * 16 + quad * 4] = acc;
}

// ---------------------------------------------------------------------------
// K3: fused softmax + cbar. Grid (16 coltiles, 8 b).
// Softmax: wave w owns heads w*4..w*4+3, shuffle-only reductions; p stored
// unnormalized (exp(s-max)) as bf16 in LDS; sum computed over quantized p.
// PV via MFMA over 32-key tiles; accumulator scaled by inv[head] at the end.
// ---------------------------------------------------------------------------
__global__ void __launch_bounds__(256) cbar_sm_kernel(
    const float* __restrict__ S, const bf16* __restrict__ seq,
    const int* __restrict__ x_len, const int* __restrict__ y_len,
    float* __restrict__ cbar) {
  const int ct = blockIdx.x, b = blockIdx.y, t = threadIdx.x;
  const int c0 = ct * 64;
  const int n = x_len[b] + y_len[b] + 3;
  const int nkt = (n + 31) >> 5;
  const int w = t >> 6, l = t & 63;
  const int lane16 = l & 15, quad = l >> 4;
  __shared__ u16 pls[16 * PLSTR_];
  __shared__ float inv16[16];
  __shared__ u16 tile[32 * 68];
  // --- per-wave softmax (4 heads/wave) ---
#pragma unroll
  for (int j = 0; j < 4; ++j) {
    const int h = w * 4 + j;
    const float* Sp = S + (size_t)h * MPAD_ + b * S_;
    float lmax = -3.0e38f;
    for (int k = l; k < n; k += 64) lmax = fmaxf(lmax, Sp[k]);
#pragma unroll
    for (int off = 32; off > 0; off >>= 1)
      lmax = fmaxf(lmax, __shfl_xor(lmax, off, 64));
    float lsum = 0.f;
    for (int k = l; k < n; k += 64) {
      float p = __expf(Sp[k] - lmax);
      u32 pb = f2bfbits(p);
      pls[h * PLSTR_ + k] = (u16)pb;
      union { u32 u; float f; } pf; pf.u = pb << 16;
      lsum += pf.f;
    }
    for (int k = n + l; k < nkt * 32; k += 64) pls[h * PLSTR_ + k] = 0;
#pragma unroll
    for (int off = 32; off > 0; off >>= 1) lsum += __shfl_xor(lsum, off, 64);
    if (l == 0) inv16[h] = 1.0f / lsum;
  }
  __syncthreads();
  // --- PV via MFMA over 32-key tiles (seq staged to LDS) ---
  const int sk = t >> 3, scg = (t & 7) * 8;
  floatx4 acc = {};
  for (int kt = 0; kt < nkt; ++kt) {
    const int k0 = kt * 32;
    __syncthreads();
    uint4 v = make_uint4(0u, 0u, 0u, 0u);
    if (k0 + sk < n)
      v = *(const uint4*)((const u16*)seq + (size_t)(b * S_ + k0 + sk) * D_ + c0 + scg);
    *(uint2*)&tile[sk * 68 + scg]     = make_uint2(v.x, v.y);
    *(uint2*)&tile[sk * 68 + scg + 4] = make_uint2(v.z, v.w);
    __syncthreads();
    bf16x8 a = *(const bf16x8*)&pls[lane16 * PLSTR_ + k0 + quad * 8];
    union { bf16x8 v; u16 u[8]; } bu;
#pragma unroll
    for (int j = 0; j < 8; ++j)
      bu.u[j] = tile[(quad * 8 + j) * 68 + w * 16 + lane16];
    acc = __builtin_amdgcn_mfma_f32_16x16x32_bf16(a, bu.v, acc, 0, 0, 0);
  }
#pragma unroll
  for (int r = 0; r < 4; ++r)
    cbar[(size_t)(b * 16 + quad * 4 + r) * D_ + c0 + w * 16 + lane16] =
        acc[r] * inv16[quad * 4 + r];
}

// ---------------------------------------------------------------------------
// Generic 8-batch GEMV: out[b][r] = in[b][:] . W[r][:] + bias[r].
// ---------------------------------------------------------------------------
template <int K, int N, int BSTR, bool INBF, bool OUTBF, bool RELU, bool PERHEAD>
__global__ void __launch_bounds__(256) gemv8_kernel(
    const void* __restrict__ in_, const float* __restrict__ W,
    const float* __restrict__ bias, void* __restrict__ out_) {
  const int t = threadIdx.x;
  const int hoff = PERHEAD ? ((blockIdx.x * 4) >> 6) * D_ : 0;
  __shared__ u16 lsb[INBF ? 8 * K : 1];
  __shared__ float lsf[INBF ? 1 : 8 * K];
  if (INBF) {
    const u16* in = (const u16*)in_;
    const int per = 8 * K / (256 * 8);
#pragma unroll
    for (int i = 0; i < per; ++i) {
      int flat = (t + i * 256) * 8;
      int b = flat / K, k = flat % K;
      *(uint4*)&lsb[flat] = *(const uint4*)(in + (size_t)b * BSTR + hoff + k);
    }
  } else {
    const float* in = (const float*)in_;
    const int per = 8 * K / (256 * 4);
#pragma unroll
    for (int i = 0; i < per; ++i) {
      int flat = (t + i * 256) * 4;
      int b = flat / K, k = flat % K;
      *(float4*)&lsf[flat] = *(const float4*)(in + (size_t)b * BSTR + hoff + k);
    }
  }
  __syncthreads();
  const int w = t >> 6, l = t & 63;
  const int r = blockIdx.x * 4 + w;
  float acc[8] = {};
#pragma unroll
  for (int ch = 0; ch < K / 256; ++ch) {
    float4 wv = *(const float4*)(W + (size_t)r * K + ch * 256 + l * 4);
#pragma unroll
    for (int b = 0; b < 8; ++b) {
      float i0, i1, i2, i3;
      if (INBF) {
        uint2 u = *(const uint2*)&lsb[b * K + ch * 256 + l * 4];
        float2 p0 = bfpair(u.x), p1 = bfpair(u.y);
        i0 = p0.x; i1 = p0.y; i2 = p1.x; i3 = p1.y;
      } else {
        const float* p = &lsf[b * K + ch * 256 + l * 4];
        i0 = p[0]; i1 = p[1]; i2 = p[2]; i3 = p[3];
      }
      acc[b] += wv.x * i0 + wv.y * i1 + wv.z * i2 + wv.w * i3;
    }
  }
#pragma unroll
  for (int off = 32; off > 0; off >>= 1)
#pragma unroll
    for (int b = 0; b < 8; ++b) acc[b] += __shfl_down(acc[b], off, 64);
  if (l == 0) {
    const float bs = bias[r];
#pragma unroll
    for (int b = 0; b < 8; ++b) {
      float v = acc[b] + bs;
      if (RELU) v = fmaxf(v, 0.f);
      if (OUTBF) ((bf16*)out_)[(size_t)b * N + r] = __float2bfloat16(v);
      else       ((float*)out_)[(size_t)b * N + r] = v;
    }
  }
}

// ---------------------------------------------------------------------------
// K6: fused LN1 + W1 GEMV + ReLU -> f1 (bf16). Grid 512 x 4 rows.
// ---------------------------------------------------------------------------
__global__ void __launch_bounds__(256) w1ln_kernel(
    const float* __restrict__ att, const float* __restrict__ cls,
    const float* __restrict__ g1, const float* __restrict__ be1,
    const float* __restrict__ W1, const float* __restrict__ b1,
    bf16* __restrict__ f1) {
  const int t = threadIdx.x;
  __shared__ float ls[8 * D_];
  __shared__ float mn[8], rsd[8];
  float4 cv = ((const float4*)cls)[t];
#pragma unroll
  for (int i = 0; i < 8; ++i) {
    float4 a = ((const float4*)(att + (size_t)i * D_))[t];
    a.x += cv.x; a.y += cv.y; a.z += cv.z; a.w += cv.w;
    *(float4*)&ls[i * D_ + t * 4] = a;
  }
  __syncthreads();
  {
    const int b = t >> 5, j = t & 31;
    const float* base = &ls[b * D_ + j * 32];
    float s = 0.f, s2 = 0.f;
#pragma unroll
    for (int k = 0; k < 32; ++k) { float v = base[k]; s += v; s2 += v * v; }
#pragma unroll
    for (int off = 16; off > 0; off >>= 1) {
      s += __shfl_down(s, off, 32);
      s2 += __shfl_down(s2, off, 32);
    }
    if (j == 0) {
      float mean = s * (1.f / D_);
      mn[b] = mean;
      rsd[b] = rsqrtf(s2 * (1.f / D_) - mean * mean + EPS_);
    }
  }
  __syncthreads();
  {
    const int b = t >> 5, j = t & 31;
    const float mean = mn[b], rs = rsd[b];
    float* base = &ls[b * D_ + j * 32];
    const float* gp = &g1[j * 32];
    const float* bp = &be1[j * 32];
#pragma unroll
    for (int k = 0; k < 32; ++k)
      base[k] = (base[k] - mean) * rs * gp[k] + bp[k];
  }
  __syncthreads();
  const int w = t >> 6, l = t & 63;
  const int r = blockIdx.x * 4 + w;
  float acc[8] = {};
#pragma unroll
  for (int ch = 0; ch < 4; ++ch) {
    float4 wv = *(const float4*)(W1 + (size_t)r * D_ + ch * 256 + l * 4);
#pragma unroll
    for (int b = 0; b < 8; ++b) {
      const float* p = &ls[b * D_ + ch * 256 + l * 4];
      acc[b] += wv.x * p[0] + wv.y * p[1] + wv.z * p[2] + wv.w * p[3];
    }
  }
#pragma unroll
  for (int off = 32; off > 0; off >>= 1)
#pragma unroll
    for (int b = 0; b < 8; ++b) acc[b] += __shfl_down(acc[b], off, 64);
  if (l == 0) {
    const float bs = b1[r];
#pragma unroll
    for (int b = 0; b < 8; ++b)
      f1[(size_t)b * FF_ + r] = __float2bfloat16(fmaxf(acc[b] + bs, 0.f));
  }
}

// ---------------------------------------------------------------------------
// K8: final LN2. Recomputes h0 = LN1(cls + att), then out = LN2(h0 + f2).
// ---------------------------------------------------------------------------
__global__ void __launch_bounds__(256) ln2_kernel(
    const float* __restrict__ cls, const float* __restrict__ att,
    const float* __restrict__ f2, const float* __restrict__ g1,
    const float* __restrict__ be1, const float* __restrict__ g2,
    const float* __restrict__ be2, float* __restrict__ out) {
  const int b = blockIdx.x, t = threadIdx.x;
  __shared__ float v[D_];
  __shared__ float red[256];
  for (int i = t; i < D_; i += 256) v[i] = cls[i] + att[(size_t)b * D_ + i];
  __syncthreads();
  float ls = 0.f;
  for (int i = t; i < D_; i += 256) ls += v[i];
  const float m1 = block_sum(ls, red) * (1.f / D_);
  float lv = 0.f;
  for (int i = t; i < D_; i += 256) { float dk = v[i] - m1; lv += dk * dk; }
  const float rs1 = rsqrtf(block_sum(lv, red) * (1.f / D_) + EPS_);
  __syncthreads();
  for (int i = t; i < D_; i += 256)
    v[i] = (v[i] - m1) * rs1 * g1[i] + be1[i] + f2[(size_t)b * D_ + i];
  __syncthreads();
  float ls2 = 0.f;
  for (int i = t; i < D_; i += 256) ls2 += v[i];
  const float m2 = block_sum(ls2, red) * (1.f / D_);
  float lv2 = 0.f;
  for (int i = t; i < D_; i += 256) { float dk = v[i] - m2; lv2 += dk * dk; }
  const float rs2 = rsqrtf(block_sum(lv2, red) * (1.f / D_) + EPS_);
  for (int i = t; i < D_; i += 256)
    out[(size_t)b * D_ + i] = (v[i] - m2) * rs2 * g2[i] + be2[i];
}

// ---------------------------------------------------------------------------
extern "C" void kernel_launch(void* const* d_in, const int* in_sizes, int n_in,
                              void* d_out, int out_size, void* d_ws, size_t ws_size,
                              hipStream_t stream) {
  (void)in_sizes; (void)n_in; (void)out_size; (void)ws_size;
  const float* x    = (const float*)d_in[0];
  const float* y    = (const float*)d_in[1];
  const float* cls  = (const float*)d_in[2];
  const float* sep  = (const float*)d_in[3];
  const float* px   = (const float*)d_in[4];
  const float* py   = (const float*)d_in[5];
  const float* Wqkv = (const float*)d_in[6];
  const float* bqkv = (const float*)d_in[7];
  const float* Wo   = (const float*)d_in[8];
  const float* bo   = (const float*)d_in[9];
  const float* W1   = (const float*)d_in[10];
  const float* b1   = (const float*)d_in[11];
  const float* W2   = (const float*)d_in[12];
  const float* b2   = (const float*)d_in[13];
  const float* g1   = (const float*)d_in[14];
  const float* be1  = (const float*)d_in[15];
  const float* g2   = (const float*)d_in[16];
  const float* be2  = (const float*)d_in[17];
  const int* xl     = (const int*)d_in[18];
  const int* yl     = (const int*)d_in[19];

  char* ws = (char*)d_ws;
  bf16*  seq   = (bf16*)(ws);                 // 17,039,360
  u16*   RT_hi = (u16*)(ws + 17039360);       //  32,768
  u16*   RT_lo = (u16*)(ws + 17072128);       //  32,768
  float* S     = (float*)(ws + 17104896);     // 532,480
  float* cbar  = (float*)(ws + 17637376);     // 524,288
  float* o0    = (float*)(ws + 18161664);     //  32,768
  float* att   = (float*)(ws + 18194432);     //  32,768
  bf16*  f1    = (bf16*)(ws + 18227200);      //  32,768
  float* f2    = (float*)(ws + 18259968);     //  32,768

  seq_qr_kernel<<<MPAD_ + 64, 256, 0, stream>>>(x, y, cls, sep, px, py,
                                                Wqkv, bqkv, xl, yl,
                                                seq, RT_hi, RT_lo);
  scores_kernel<<<130, 256, 0, stream>>>(seq, RT_hi, RT_lo, xl, yl, S);
  cbar_sm_kernel<<<dim3(16, 8), 256, 0, stream>>>(S, seq, xl, yl, cbar);
  gemv8_kernel<1024, 1024, 16384, false, false, false, true>
      <<<256, 256, 0, stream>>>(cbar, Wqkv + (size_t)2048 * 1024, bqkv + 2048, o0);
  gemv8_kernel<1024, 1024, 1024, false, false, false, false>
      <<<256, 256, 0, stream>>>(o0, Wo, bo, att);
  w1ln_kernel<<<512, 256, 0, stream>>>(att, cls, g1, be1, W1, b1, f1);
  gemv8_kernel<2048, 1024, 2048, true, false, false, false>
      <<<256, 256, 0, stream>>>(f1, W2, b2, f2);
  ln2_kernel<<<B_, 256, 0, stream>>>(cls, att, f2, g1, be1, g2, be2,
                                     (float*)d_out);
}

// Round 8
// 195.587 us; speedup vs baseline: 2.4541x; 1.0827x over previous
//
#include <hip/hip_runtime.h>
#include <hip/hip_bf16.h>

#define D_ 1024
#define H_ 16
#define FF_ 2048
#define B_ 8
#define S_ 1027
#define MPAD_ 8320   /* 130 * 64 */
#define PSTR_ 1056   /* padded key stride for P (mult 32, covers 1027) */
#define EPS_ 1e-5f

typedef __hip_bfloat16 bf16;
typedef unsigned short u16;
typedef unsigned int u32;
typedef __attribute__((ext_vector_type(4))) float floatx4;
typedef __bf16 bf16x8 __attribute__((ext_vector_type(8)));

__device__ __forceinline__ float2 bfpair(u32 u) {
  union { u32 u; float f; } lo, hi;
  lo.u = u << 16; hi.u = u & 0xffff0000u;
  return make_float2(lo.f, hi.f);
}

__device__ __forceinline__ u32 f2bfbits(float f) {
  union { bf16 h; u16 u; } cv; cv.h = __float2bfloat16(f); return (u32)cv.u;
}

__device__ __forceinline__ float block_sum(float x, float* red) {
  const int t = threadIdx.x;
  __syncthreads();
  red[t] = x;
  __syncthreads();
  for (int s = 128; s > 0; s >>= 1) {
    if (t < s) red[t] += red[t + s];
    __syncthreads();
  }
  return red[0];
}

__device__ __forceinline__ float block_max(float x, float* red) {
  const int t = threadIdx.x;
  __syncthreads();
  red[t] = x;
  __syncthreads();
  for (int s = 128; s > 0; s >>= 1) {
    if (t < s) red[t] = fmaxf(red[t], red[t + s]);
    __syncthreads();
  }
  return red[0];
}

// ---------------------------------------------------------------------------
// K1: build merged sequence as bf16, coalesced (block per row). Invalid rows
// are NOT written (downstream never reads them).
// ---------------------------------------------------------------------------
__global__ void __launch_bounds__(256) build_seq_kernel(
    const float* __restrict__ x, const float* __restrict__ y,
    const float* __restrict__ cls, const float* __restrict__ sep,
    const float* __restrict__ px, const float* __restrict__ py,
    const int* __restrict__ x_len, const int* __restrict__ y_len,
    bf16* __restrict__ seq) {
  const int m = blockIdx.x, t = threadIdx.x;
  const int b = m / S_;
  const int s = m - b * S_;
  if (b >= B_) return;
  const float* src = nullptr;
  const float* add = nullptr;
  const int lx = x_len[b], ly = y_len[b];
  if (s == 0) src = cls;
  else if (s <= lx) { src = x + ((size_t)b * 512 + (s - 1)) * D_; add = px; }
  else if (s == lx + 1) src = sep;
  else if (s <= lx + ly + 1) { src = y + ((size_t)b * 512 + (s - lx - 2)) * D_; add = py; }
  else if (s == lx + ly + 2) src = sep;
  if (!src) return;
  float4 sv = ((const float4*)src)[t];
  if (add) {
    float4 av = ((const float4*)add)[t];
    sv.x += av.x; sv.y += av.y; sv.z += av.z; sv.w += av.w;
  }
  uint2 o;
  o.x = f2bfbits(sv.x) | (f2bfbits(sv.y) << 16);
  o.y = f2bfbits(sv.z) | (f2bfbits(sv.w) << 16);
  ((uint2*)(seq + (size_t)m * D_))[t] = o;
}

// ---------------------------------------------------------------------------
// K2: q0s[r] = (Wq[r,:].cls + bq[r]) / 8.  Grid 256 blocks, wave per row.
// (R3's proven qproj — 256 blocks, fast ramp.)
// ---------------------------------------------------------------------------
__global__ void __launch_bounds__(256) qproj_kernel(
    const float* __restrict__ cls, const float* __restrict__ Wqkv,
    const float* __restrict__ bqkv, float* __restrict__ q0s) {
  __shared__ float cl[D_];
  const int t = threadIdx.x;
  *(float4*)&cl[t * 4] = ((const float4*)cls)[t];
  __syncthreads();
  const int w = t >> 6, l = t & 63;
  const int r = blockIdx.x * 4 + w;
  float acc = 0.f;
#pragma unroll
  for (int ch = 0; ch < 4; ++ch) {
    float4 wv = *(const float4*)(Wqkv + (size_t)r * D_ + ch * 256 + l * 4);
    const float* c4 = &cl[ch * 256 + l * 4];
    acc += wv.x * c4[0] + wv.y * c4[1] + wv.z * c4[2] + wv.w * c4[3];
  }
#pragma unroll
  for (int off = 32; off > 0; off >>= 1) acc += __shfl_down(acc, off, 64);
  if (l == 0) q0s[r] = (acc + bqkv[r]) * 0.125f;
}

// ---------------------------------------------------------------------------
// K3: R[d][h] = sum_e Wk[h*64+e][d] * q0s[h*64+e], split to bf16 hi/lo.
// RT_hi/RT_lo layout [16][1024]. Grid (4 colchunks, 16 heads). (R3 proven.)
// ---------------------------------------------------------------------------
__global__ void __launch_bounds__(256) rproj_kernel(
    const float* __restrict__ Wqkv, const float* __restrict__ q0s,
    u16* __restrict__ RT_hi, u16* __restrict__ RT_lo) {
  const int h = blockIdx.y, cc = blockIdx.x, t = threadIdx.x;
  __shared__ float qs[64];
  if (t < 64) qs[t] = q0s[h * 64 + t];
  __syncthreads();
  const int c = cc * 256 + t;
  const float* Wk = Wqkv + (size_t)(D_ + h * 64) * D_ + c;
  float acc = 0.f;
#pragma unroll 8
  for (int e = 0; e < 64; ++e) acc += Wk[(size_t)e * D_] * qs[e];
  const u32 hb = f2bfbits(acc);
  union { u32 u; float f; } hv; hv.u = hb << 16;
  RT_hi[h * D_ + c] = (u16)hb;
  RT_lo[h * D_ + c] = (u16)f2bfbits(acc - hv.f);
}

// ---------------------------------------------------------------------------
// K4: scores S[h][m] = seq[m,:] . R[:,h] via MFMA 16x16x32 (hi+lo).
// Grid 130 m-tiles of 64 rows; early-exit fully-invalid tiles. (Proven.)
// ---------------------------------------------------------------------------
__global__ void __launch_bounds__(256) scores_kernel(
    const bf16* __restrict__ seq, const u16* __restrict__ RT_hi,
    const u16* __restrict__ RT_lo, const int* __restrict__ x_len,
    const int* __restrict__ y_len, float* __restrict__ S) {
  const int m0 = blockIdx.x * 64;
  bool valid = false;
#pragma unroll
  for (int b = 0; b < B_; ++b) {
    int rs = b * S_, re = rs + x_len[b] + y_len[b] + 3;
    if (m0 < re && m0 + 64 > rs) valid = true;
  }
  if (!valid) return;
  const int t = threadIdx.x;
  const int w = t >> 6, lane = t & 63, lane16 = lane & 15, quad = lane >> 4;
  const int row = m0 + w * 16 + lane16;
  const u16* arow = (const u16*)seq + (size_t)row * D_ + quad * 8;
  const u16* bh = RT_hi + lane16 * D_ + quad * 8;
  const u16* bl = RT_lo + lane16 * D_ + quad * 8;
  floatx4 acc = {};
#pragma unroll 4
  for (int kt = 0; kt < 32; ++kt) {
    bf16x8 a  = *(const bf16x8*)(arow + kt * 32);
    bf16x8 vh = *(const bf16x8*)(bh + kt * 32);
    bf16x8 vl = *(const bf16x8*)(bl + kt * 32);
    acc = __builtin_amdgcn_mfma_f32_16x16x32_bf16(a, vh, acc, 0, 0, 0);
    acc = __builtin_amdgcn_mfma_f32_16x16x32_bf16(a, vl, acc, 0, 0, 0);
  }
  *(floatx4*)&S[(size_t)lane16 * MPAD_ + m0 + w * 16 + quad * 4] = acc;
}

// ---------------------------------------------------------------------------
// K5: softmax per (h, b); writes normalized p as bf16, zero-padded to PSTR_.
// (Proven.)
// ---------------------------------------------------------------------------
__global__ void __launch_bounds__(256) softmax_kernel(
    const float* __restrict__ S, const int* __restrict__ x_len,
    const int* __restrict__ y_len, u16* __restrict__ P) {
  const int h = blockIdx.x, b = blockIdx.y, t = threadIdx.x;
  const int n = x_len[b] + y_len[b] + 3;
  __shared__ float sc[PSTR_];
  __shared__ float red[256];
  const float* Sp = S + (size_t)h * MPAD_ + b * S_;
  float lmax = -3.0e38f;
  for (int k = t; k < n; k += 256) {
    float s = Sp[k];
    sc[k] = s;
    lmax = fmaxf(lmax, s);
  }
  const float gmax = block_max(lmax, red);
  float lsum = 0.f;
  for (int k = t; k < n; k += 256) {
    float p = __expf(sc[k] - gmax);
    sc[k] = p;
    lsum += p;
  }
  const float inv = 1.0f / block_sum(lsum, red);
  u16* Pp = P + (size_t)(h * 8 + b) * PSTR_;
  for (int k = t; k < PSTR_; k += 256)
    Pp[k] = (k < n) ? (u16)f2bfbits(sc[k] * inv) : (u16)0;
}

// ---------------------------------------------------------------------------
// K6: cbar[b][h][c] = sum_k p[h][k] * seq[bS+k][c] via MFMA (M=16 heads).
// Grid (16 coltiles x 8 b); 32-key LDS tiles. (Proven.)
// ---------------------------------------------------------------------------
__global__ void __launch_bounds__(256) cbar_kernel(
    const bf16* __restrict__ seq, const u16* __restrict__ P,
    const int* __restrict__ x_len, const int* __restrict__ y_len,
    float* __restrict__ cbar) {
  const int ct = blockIdx.x, b = blockIdx.y, t = threadIdx.x;
  const int c0 = ct * 64;
  const int n = x_len[b] + y_len[b] + 3;
  const int nkt = (n + 31) >> 5;
  __shared__ u16 tile[32 * 68];
  const int w = t >> 6, lane = t & 63, lane16 = lane & 15, quad = lane >> 4;
  const int sk = t >> 3, scg = (t & 7) * 8;
  floatx4 acc = {};
  for (int kt = 0; kt < nkt; ++kt) {
    const int k0 = kt * 32;
    __syncthreads();
    uint4 v = make_uint4(0u, 0u, 0u, 0u);
    if (k0 + sk < n)
      v = *(const uint4*)((const u16*)seq + (size_t)(b * S_ + k0 + sk) * D_ + c0 + scg);
    *(uint2*)&tile[sk * 68 + scg]     = make_uint2(v.x, v.y);
    *(uint2*)&tile[sk * 68 + scg + 4] = make_uint2(v.z, v.w);
    __syncthreads();
    bf16x8 a = *(const bf16x8*)(P + (size_t)(lane16 * 8 + b) * PSTR_ + k0 + quad * 8);
    union { bf16x8 v; u16 u[8]; } bu;
#pragma unroll
    for (int j = 0; j < 8; ++j)
      bu.u[j] = tile[(quad * 8 + j) * 68 + w * 16 + lane16];
    acc = __builtin_amdgcn_mfma_f32_16x16x32_bf16(a, bu.v, acc, 0, 0, 0);
  }
#pragma unroll
  for (int r = 0; r < 4; ++r)
    cbar[(size_t)(b * 16 + quad * 4 + r) * D_ + c0 + w * 16 + lane16] = acc[r];
}

// ---------------------------------------------------------------------------
// Generic 8-batch GEMV: out[b][r] = in[b][:] . W[r][:] + bias[r]. (Proven.)
// ---------------------------------------------------------------------------
template <int K, int N, int BSTR, bool INBF, bool OUTBF, bool RELU, bool PERHEAD>
__global__ void __launch_bounds__(256) gemv8_kernel(
    const void* __restrict__ in_, const float* __restrict__ W,
    const float* __restrict__ bias, void* __restrict__ out_) {
  const int t = threadIdx.x;
  const int hoff = PERHEAD ? ((blockIdx.x * 4) >> 6) * D_ : 0;
  __shared__ u16 lsb[INBF ? 8 * K : 1];
  __shared__ float lsf[INBF ? 1 : 8 * K];
  if (INBF) {
    const u16* in = (const u16*)in_;
    const int per = 8 * K / (256 * 8);
#pragma unroll
    for (int i = 0; i < per; ++i) {
      int flat = (t + i * 256) * 8;
      int b = flat / K, k = flat % K;
      *(uint4*)&lsb[flat] = *(const uint4*)(in + (size_t)b * BSTR + hoff + k);
    }
  } else {
    const float* in = (const float*)in_;
    const int per = 8 * K / (256 * 4);
#pragma unroll
    for (int i = 0; i < per; ++i) {
      int flat = (t + i * 256) * 4;
      int b = flat / K, k = flat % K;
      *(float4*)&lsf[flat] = *(const float4*)(in + (size_t)b * BSTR + hoff + k);
    }
  }
  __syncthreads();
  const int w = t >> 6, l = t & 63;
  const int r = blockIdx.x * 4 + w;
  float acc[8] = {};
#pragma unroll
  for (int ch = 0; ch < K / 256; ++ch) {
    float4 wv = *(const float4*)(W + (size_t)r * K + ch * 256 + l * 4);
#pragma unroll
    for (int b = 0; b < 8; ++b) {
      float i0, i1, i2, i3;
      if (INBF) {
        uint2 u = *(const uint2*)&lsb[b * K + ch * 256 + l * 4];
        float2 p0 = bfpair(u.x), p1 = bfpair(u.y);
        i0 = p0.x; i1 = p0.y; i2 = p1.x; i3 = p1.y;
      } else {
        const float* p = &lsf[b * K + ch * 256 + l * 4];
        i0 = p[0]; i1 = p[1]; i2 = p[2]; i3 = p[3];
      }
      acc[b] += wv.x * i0 + wv.y * i1 + wv.z * i2 + wv.w * i3;
    }
  }
#pragma unroll
  for (int off = 32; off > 0; off >>= 1)
#pragma unroll
    for (int b = 0; b < 8; ++b) acc[b] += __shfl_down(acc[b], off, 64);
  if (l == 0) {
    const float bs = bias[r];
#pragma unroll
    for (int b = 0; b < 8; ++b) {
      float v = acc[b] + bs;
      if (RELU) v = fmaxf(v, 0.f);
      if (OUTBF) ((bf16*)out_)[(size_t)b * N + r] = __float2bfloat16(v);
      else       ((float*)out_)[(size_t)b * N + r] = v;
    }
  }
}

// ---------------------------------------------------------------------------
// K9: fused LN1 + W1 GEMV + ReLU -> f1 (bf16). Grid 512 x 4 rows.
// (Measured ~neutral vs split ln1+gemv; saves one dispatch.)
// ---------------------------------------------------------------------------
__global__ void __launch_bounds__(256) w1ln_kernel(
    const float* __restrict__ att, const float* __restrict__ cls,
    const float* __restrict__ g1, const float* __restrict__ be1,
    const float* __restrict__ W1, const float* __restrict__ b1,
    bf16* __restrict__ f1) {
  const int t = threadIdx.x;
  __shared__ float ls[8 * D_];
  __shared__ float mn[8], rsd[8];
  float4 cv = ((const float4*)cls)[t];
#pragma unroll
  for (int i = 0; i < 8; ++i) {
    float4 a = ((const float4*)(att + (size_t)i * D_))[t];
    a.x += cv.x; a.y += cv.y; a.z += cv.z; a.w += cv.w;
    *(float4*)&ls[i * D_ + t * 4] = a;
  }
  __syncthreads();
  {
    const int b = t >> 5, j = t & 31;
    const float* base = &ls[b * D_ + j * 32];
    float s = 0.f, s2 = 0.f;
#pragma unroll
    for (int k = 0; k < 32; ++k) { float v = base[k]; s += v; s2 += v * v; }
#pragma unroll
    for (int off = 16; off > 0; off >>= 1) {
      s += __shfl_down(s, off, 32);
      s2 += __shfl_down(s2, off, 32);
    }
    if (j == 0) {
      float mean = s * (1.f / D_);
      mn[b] = mean;
      rsd[b] = rsqrtf(s2 * (1.f / D_) - mean * mean + EPS_);
    }
  }
  __syncthreads();
  {
    const int b = t >> 5, j = t & 31;
    const float mean = mn[b], rs = rsd[b];
    float* base = &ls[b * D_ + j * 32];
    const float* gp = &g1[j * 32];
    const float* bp = &be1[j * 32];
#pragma unroll
    for (int k = 0; k < 32; ++k)
      base[k] = (base[k] - mean) * rs * gp[k] + bp[k];
  }
  __syncthreads();
  const int w = t >> 6, l = t & 63;
  const int r = blockIdx.x * 4 + w;
  float acc[8] = {};
#pragma unroll
  for (int ch = 0; ch < 4; ++ch) {
    float4 wv = *(const float4*)(W1 + (size_t)r * D_ + ch * 256 + l * 4);
#pragma unroll
    for (int b = 0; b < 8; ++b) {
      const float* p = &ls[b * D_ + ch * 256 + l * 4];
      acc[b] += wv.x * p[0] + wv.y * p[1] + wv.z * p[2] + wv.w * p[3];
    }
  }
#pragma unroll
  for (int off = 32; off > 0; off >>= 1)
#pragma unroll
    for (int b = 0; b < 8; ++b) acc[b] += __shfl_down(acc[b], off, 64);
  if (l == 0) {
    const float bs = b1[r];
#pragma unroll
    for (int b = 0; b < 8; ++b)
      f1[(size_t)b * FF_ + r] = __float2bfloat16(fmaxf(acc[b] + bs, 0.f));
  }
}

// ---------------------------------------------------------------------------
// K11: final LN2. Recomputes h0 = LN1(cls + att), then out = LN2(h0 + f2).
// ---------------------------------------------------------------------------
__global__ void __launch_bounds__(256) ln2_kernel(
    const float* __restrict__ cls, const float* __restrict__ att,
    const float* __restrict__ f2, const float* __restrict__ g1,
    const float* __restrict__ be1, const float* __restrict__ g2,
    const float* __restrict__ be2, float* __restrict__ out) {
  const int b = blockIdx.x, t = threadIdx.x;
  __shared__ float v[D_];
  __shared__ float red[256];
  for (int i = t; i < D_; i += 256) v[i] = cls[i] + att[(size_t)b * D_ + i];
  __syncthreads();
  float ls = 0.f;
  for (int i = t; i < D_; i += 256) ls += v[i];
  const float m1 = block_sum(ls, red) * (1.f / D_);
  float lv = 0.f;
  for (int i = t; i < D_; i += 256) { float dk = v[i] - m1; lv += dk * dk; }
  const float rs1 = rsqrtf(block_sum(lv, red) * (1.f / D_) + EPS_);
  __syncthreads();
  for (int i = t; i < D_; i += 256)
    v[i] = (v[i] - m1) * rs1 * g1[i] + be1[i] + f2[(size_t)b * D_ + i];
  __syncthreads();
  float ls2 = 0.f;
  for (int i = t; i < D_; i += 256) ls2 += v[i];
  const float m2 = block_sum(ls2, red) * (1.f / D_);
  float lv2 = 0.f;
  for (int i = t; i < D_; i += 256) { float dk = v[i] - m2; lv2 += dk * dk; }
  const float rs2 = rsqrtf(block_sum(lv2, red) * (1.f / D_) + EPS_);
  for (int i = t; i < D_; i += 256)
    out[(size_t)b * D_ + i] = (v[i] - m2) * rs2 * g2[i] + be2[i];
}

// ---------------------------------------------------------------------------
extern "C" void kernel_launch(void* const* d_in, const int* in_sizes, int n_in,
                              void* d_out, int out_size, void* d_ws, size_t ws_size,
                              hipStream_t stream) {
  (void)in_sizes; (void)n_in; (void)out_size; (void)ws_size;
  const float* x    = (const float*)d_in[0];
  const float* y    = (const float*)d_in[1];
  const float* cls  = (const float*)d_in[2];
  const float* sep  = (const float*)d_in[3];
  const float* px   = (const float*)d_in[4];
  const float* py   = (const float*)d_in[5];
  const float* Wqkv = (const float*)d_in[6];
  const float* bqkv = (const float*)d_in[7];
  const float* Wo   = (const float*)d_in[8];
  const float* bo   = (const float*)d_in[9];
  const float* W1   = (const float*)d_in[10];
  const float* b1   = (const float*)d_in[11];
  const float* W2   = (const float*)d_in[12];
  const float* b2   = (const float*)d_in[13];
  const float* g1   = (const float*)d_in[14];
  const float* be1  = (const float*)d_in[15];
  const float* g2   = (const float*)d_in[16];
  const float* be2  = (const float*)d_in[17];
  const int* xl     = (const int*)d_in[18];
  const int* yl     = (const int*)d_in[19];

  char* ws = (char*)d_ws;
  bf16*  seq   = (bf16*)(ws);                 // 17,039,360
  float* q0s   = (float*)(ws + 17039360);     //   4,096
  u16*   RT_hi = (u16*)(ws + 17043456);       //  32,768
  u16*   RT_lo = (u16*)(ws + 17076224);       //  32,768
  float* S     = (float*)(ws + 17108992);     // 532,480
  u16*   P     = (u16*)(ws + 17641472);       // 270,336
  float* cbar  = (float*)(ws + 17911808);     // 524,288
  float* o0    = (float*)(ws + 18436096);     //  32,768
  float* att   = (float*)(ws + 18468864);     //  32,768
  bf16*  f1    = (bf16*)(ws + 18501632);      //  32,768
  float* f2    = (float*)(ws + 18534400);     //  32,768

  build_seq_kernel<<<MPAD_, 256, 0, stream>>>(x, y, cls, sep, px, py, xl, yl, seq);
  qproj_kernel<<<256, 256, 0, stream>>>(cls, Wqkv, bqkv, q0s);
  rproj_kernel<<<dim3(4, 16), 256, 0, stream>>>(Wqkv, q0s, RT_hi, RT_lo);
  scores_kernel<<<130, 256, 0, stream>>>(seq, RT_hi, RT_lo, xl, yl, S);
  softmax_kernel<<<dim3(16, 8), 256, 0, stream>>>(S, xl, yl, P);
  cbar_kernel<<<dim3(16, 8), 256, 0, stream>>>(seq, P, xl, yl, cbar);
  gemv8_kernel<1024, 1024, 16384, false, false, false, true>
      <<<256, 256, 0, stream>>>(cbar, Wqkv + (size_t)2048 * 1024, bqkv + 2048, o0);
  gemv8_kernel<1024, 1024, 1024, false, false, false, false>
      <<<256, 256, 0, stream>>>(o0, Wo, bo, att);
  w1ln_kernel<<<512, 256, 0, stream>>>(att, cls, g1, be1, W1, b1, f1);
  gemv8_kernel<2048, 1024, 2048, true, false, false, false>
      <<<256, 256, 0, stream>>>(f1, W2, b2, f2);
  ln2_kernel<<<B_, 256, 0, stream>>>(cls, att, f2, g1, be1, g2, be2,
                                     (float*)d_out);
}